// Round 10
// baseline (109.352 us; speedup 1.0000x reference)
//
#include <hip/hip_runtime.h>

// Problem constants
#define B_  8192
#define C_  64
#define K_  256
#define D_  64
#define WROWS 64               // b-rows per wave (4 MFMA sub-tiles)
#define GX  (B_ / (8 * WROWS)) // 16 blocks along b (8 waves/block)
#define BC_ (B_ * C_)
#define BN_EPS 1e-5

#define WCAP_C 1024            // per-channel referee list capacity
#define DELTA  2.5e-3f         // top-2 gap flag band (validated r4/r9)

typedef _Float16 f16x8 __attribute__((ext_vector_type(8)));
typedef float    f32x4 __attribute__((ext_vector_type(4)));

// XOR swizzle for [row][128B] f16 plane: kills 32-way bank conflict on b128.
__device__ __forceinline__ int swz(int row, int dbyte) {
    return (row * 128 + dbyte) ^ ((row & 7) << 4);
}

// plain-cast f32x8 -> f16x8 (known-good RTNE conversion)
__device__ __forceinline__ f16x8 cvt8(const float* p) {
    float4 u0 = *(const float4*)p;
    float4 u1 = *(const float4*)(p + 4);
    return (f16x8){(_Float16)u0.x, (_Float16)u0.y, (_Float16)u0.z, (_Float16)u0.w,
                   (_Float16)u1.x, (_Float16)u1.y, (_Float16)u1.z, (_Float16)u1.w};
}

// merge two packed (best, second) pairs over disjoint k-sets
#define MERGE2(B1, S1, B2, S2)                                              \
    {                                                                       \
        const float lo_ = fminf(B1, B2);                                    \
        B1 = fmaxf(B1, B2);                                                 \
        S1 = fmaxf(lo_, fmaxf(S1, S2));                                     \
    }

// ---------------------------------------------------------------------------
// Prep: per-channel centroid column sums + zero referee counters.
// grid (C_), 256 thr: thread (seg = t>>6, d = t&63) sums k in [seg*64, +64)
// of column d (coalesced across d), LDS-reduce 4 segments.
// ---------------------------------------------------------------------------
__global__ __launch_bounds__(256) void dpq_prep(
    const float* __restrict__ cent, float* __restrict__ csum,
    int* __restrict__ wcount)
{
    __shared__ float pacc[4][D_];
    const int c = blockIdx.x, t = threadIdx.x;
    const int d = t & 63, seg = t >> 6;
    const float* g = cent + (size_t)c * K_ * D_ + (size_t)seg * 64 * D_ + d;
    float s = 0.f;
#pragma unroll 8
    for (int k = 0; k < 64; ++k) s += g[(size_t)k * D_];
    pacc[seg][d] = s;
    __syncthreads();
    if (t < D_)
        csum[c * D_ + t] = (pacc[0][t] + pacc[1][t]) + (pacc[2][t] + pacc[3][t]);
    if (t == 0) wcount[c] = 0;
}

// ---------------------------------------------------------------------------
// Pass 1: single-pass f16 MFMA scoring. 512 thr, 32 KiB plane + 2 KiB cs-tile.
// Wave owns 64 b-rows (4 sub-tiles); 16 k-steps + virtual sum-step (Sum_k r).
// Per-T immediate epilogue (low VGPR) -> 6 waves/SIMD occupancy target.
// ---------------------------------------------------------------------------
__global__ __launch_bounds__(512, 6) void dpq_mfma(
    const float* __restrict__ x,        // (B, C, D)
    const float* __restrict__ cent,     // (C, K, D)
    const float* __restrict__ gamma,    // (C)
    const float* __restrict__ csum,     // (C, D) centroid column sums
    float* __restrict__ out,            // [codes BC][raw mse BC][centroids]
    float* __restrict__ part_sum,       // (C, GX)
    float* __restrict__ part_sq,        // (C, GX)
    int* __restrict__ wcount,           // (C)
    int* __restrict__ worklist)         // (C, WCAP_C) stores b
{
    __shared__ char lds[34816];         // [0,32K) k-plane | [32K,34K) cs-tile
    const int c   = blockIdx.y;
    const int tid = threadIdx.x;
    const float sgn = (gamma[c] < 0.0f) ? -1.0f : 1.0f;   // fold BN sign

    // ---- stage centroids: 512 threads, each converts half a k-row ----
    {
        const int row = tid >> 1, half = tid & 1;
        const float* g = cent + ((size_t)c * K_ + row) * D_ + half * 32;
#pragma unroll
        for (int q = 0; q < 4; ++q) {
            float v[8];
#pragma unroll
            for (int j = 0; j < 8; ++j) v[j] = g[q * 8 + j] * sgn;
            f16x8 h = {(_Float16)v[0], (_Float16)v[1], (_Float16)v[2], (_Float16)v[3],
                       (_Float16)v[4], (_Float16)v[5], (_Float16)v[6], (_Float16)v[7]};
            *(f16x8*)(lds + swz(row, half * 64 + q * 16)) = h;
        }
    }
    // ---- stage cs-tile: row 0 = sign-folded centroid sum, rows 1-15 = 0 ----
    if (tid < 128) {
        const int row = tid >> 3, q = tid & 7;
        f16x8 h = {0, 0, 0, 0, 0, 0, 0, 0};
        if (row == 0) {
            const float* cs = csum + c * D_ + q * 8;
#pragma unroll
            for (int j = 0; j < 8; ++j) h[j] = (_Float16)(cs[j] * sgn);
        }
        *(f16x8*)(lds + 32768 + swz(row, q * 16)) = h;
    }
    __syncthreads();

    const int wid = tid >> 6, lane = tid & 63;
    const int col = lane & 15, grp = lane >> 4;
    const unsigned g4 = (unsigned)(grp * 4);
    const int b0 = blockIdx.x * (8 * WROWS) + wid * WROWS;

    // x fragments: 4 b-subtiles (T) x 2 d-halves
    f16x8 xfa[4], xfb[4];
    {
        const float* xb = x + ((size_t)(b0 + col) * C_ + c) * D_ + grp * 8;
        const size_t st16 = (size_t)16 * C_ * D_;
#pragma unroll
        for (int T = 0; T < 4; ++T) {
            xfa[T] = cvt8(xb + T * st16);
            xfb[T] = cvt8(xb + T * st16 + 32);
        }
    }

    float taccs[4] = {0.f, 0.f, 0.f, 0.f};   // fed by virtual sum-step only
    float taccq[4] = {0.f, 0.f, 0.f, 0.f};
    float bestv[4], secv[4];
#pragma unroll
    for (int T = 0; T < 4; ++T) { bestv[T] = -3.4e38f; secv[T] = -3.4e38f; }

#pragma unroll 4
    for (int t = 0; t < 16; ++t) {
        const f16x8 a0 = *(const f16x8*)(lds + swz(t * 16 + col,      grp * 16));
        const f16x8 a1 = *(const f16x8*)(lds + swz(t * 16 + col, 64 + grp * 16));
        const unsigned kt = ((unsigned)t << 4) | g4;   // t*16 + grp*4

#pragma unroll
        for (int T = 0; T < 4; ++T) {
            f32x4 acc = {0.f, 0.f, 0.f, 0.f};
            acc = __builtin_amdgcn_mfma_f32_16x16x32_f16(a0, xfa[T], acc, 0, 0, 0);
            acc = __builtin_amdgcn_mfma_f32_16x16x32_f16(a1, xfb[T], acc, 0, 0, 0);
#pragma unroll
            for (int j = 0; j < 4; ++j) {
                const float r = acc[j];
                taccq[T] = fmaf(r, r, taccq[T]);
                const float pk = __uint_as_float(
                    (__float_as_uint(r) & 0xFFFFFF00u) | (kt + j));
                secv[T]  = __builtin_amdgcn_fmed3f(pk, bestv[T], secv[T]);
                bestv[T] = fmaxf(bestv[T], pk);
            }
        }
    }

    // ---- virtual sum-step: row 0 of cs-tile = sum over all k ----
    {
        const f16x8 a0v = *(const f16x8*)(lds + 32768 + swz(col,      grp * 16));
        const f16x8 a1v = *(const f16x8*)(lds + 32768 + swz(col, 64 + grp * 16));
#pragma unroll
        for (int T = 0; T < 4; ++T) {
            f32x4 pv = {0.f, 0.f, 0.f, 0.f};
            pv = __builtin_amdgcn_mfma_f32_16x16x32_f16(a0v, xfa[T], pv, 0, 0, 0);
            pv = __builtin_amdgcn_mfma_f32_16x16x32_f16(a1v, xfb[T], pv, 0, 0, 0);
            taccs[T] += pv[0];   // nonzero only on k-row-0 lanes
        }
    }

    // ---- cross-lane top-2 merge (same-col lanes differ in bits 4,5) ----
#pragma unroll
    for (int T = 0; T < 4; ++T) {
        float bv = bestv[T], sv = secv[T];
#pragma unroll
        for (int m = 16; m <= 32; m <<= 1) {
            const float ob = __shfl_xor(bv, m);
            const float os = __shfl_xor(sv, m);
            MERGE2(bv, sv, ob, os);
        }
        if (grp == 0) {
            const int b = b0 + T * 16 + col;
            const size_t idx = (size_t)b * C_ + c;
            const unsigned bits = __float_as_uint(bv);
            out[idx] = (float)(bits & 255u);                       // code
            out[(size_t)BC_ + idx] = __uint_as_float(bits & 0xFFFFFF00u);
            if (bv - sv < DELTA) {
                const int slot = atomicAdd(&wcount[c], 1);
                if (slot < WCAP_C) worklist[c * WCAP_C + slot] = b;
            }
        }
    }

    // ---- channel sum / sumsq block reduction ----
    float accs = (taccs[0] + taccs[1]) + (taccs[2] + taccs[3]);
    float accq = (taccq[0] + taccq[1]) + (taccq[2] + taccq[3]);
#pragma unroll
    for (int m = 1; m <= 32; m <<= 1) {
        accs += __shfl_xor(accs, m);
        accq += __shfl_xor(accq, m);
    }
    __syncthreads();                    // plane dead; reuse LDS
    float* red = (float*)lds;
    if (lane == 0) { red[wid] = accs; red[8 + wid] = accq; }
    __syncthreads();
    if (tid == 0) {
        float s = 0.f, q = 0.f;
#pragma unroll
        for (int w = 0; w < 8; ++w) { s += red[w]; q += red[8 + w]; }
        part_sum[c * GX + blockIdx.x] = s;
        part_sq [c * GX + blockIdx.x] = q;
    }
}

// ---------------------------------------------------------------------------
// Referee: exact fp64 re-score of flagged pairs, channel-bucketed.
// grid (64, 4): block (c, s) stages channel c's centroids (f32, bank-swizzled)
// in 64 KiB LDS once; each WAVE takes one entry (lane = 4 k's), fp64 dot.
// ---------------------------------------------------------------------------
__global__ __launch_bounds__(256) void dpq_referee(
    const float* __restrict__ x,
    const float* __restrict__ cent,
    const float* __restrict__ gamma,
    const int* __restrict__ wcount,
    const int* __restrict__ worklist,
    float* __restrict__ out)
{
    __shared__ float cl[K_ * D_];       // 64 KiB exact centroids
    const int c = blockIdx.x;
    int n = wcount[c];
    if (n > WCAP_C) n = WCAP_C;
    if (n <= 0) return;
    const int t = threadIdx.x;          // 0..255 = k row to stage
    const float sgnf = (gamma[c] < 0.0f) ? -1.0f : 1.0f;

    // stage row t with d-swizzle (d ^ (k&31)) -> conflict-free lane reads
    {
        const float* g = cent + ((size_t)c * K_ + t) * D_;
#pragma unroll 8
        for (int d = 0; d < D_; ++d)
            cl[t * D_ + (d ^ (t & 31))] = g[d];
    }
    __syncthreads();

    const int wid = t >> 6, lane = t & 63;
    for (int i = blockIdx.y * 4 + wid; i < n; i += gridDim.y * 4) {
        const int b = worklist[c * WCAP_C + i];
        const float* xr = x + ((size_t)b * C_ + c) * D_;
        double bv = -1.0e300;
        int bk = 0;
#pragma unroll
        for (int q = 0; q < 4; ++q) {
            const int k = q * 64 + lane;            // ascending per lane
            const int sw = k & 31;
            double s = 0.0;
#pragma unroll 8
            for (int d = 0; d < D_; ++d)
                s += (double)xr[d] * (double)cl[k * D_ + (d ^ sw)];
            s *= (double)sgnf;
            if (s > bv) { bv = s; bk = k; }
        }
#pragma unroll
        for (int m = 1; m <= 32; m <<= 1) {
            const double ov = __shfl_xor(bv, m);
            const int   ok = __shfl_xor(bk, m);
            if (ov > bv || (ov == bv && ok < bk)) { bv = ov; bk = ok; }
        }
        if (lane == 0) {
            const size_t idx = (size_t)b * C_ + c;
            out[idx] = (float)bk;
            out[(size_t)BC_ + idx] = (float)bv;
        }
    }
}

// ---------------------------------------------------------------------------
// Apply (fused stats + affine + centroid passthrough).
// ---------------------------------------------------------------------------
__global__ __launch_bounds__(256) void dpq_apply(
    float* __restrict__ out,
    const float* __restrict__ part_sum,
    const float* __restrict__ part_sq,
    const float* __restrict__ gamma,
    const float* __restrict__ beta,
    const float* __restrict__ cent)
{
    __shared__ float sc_s[C_], sh_s[C_];
    const int tid = threadIdx.x;
    if (tid < C_) {
        double s = 0.0, q = 0.0;
#pragma unroll
        for (int i = 0; i < GX; ++i) {
            s += (double)part_sum[tid * GX + i];
            q += (double)part_sq [tid * GX + i];
        }
        const double n    = (double)B_ * (double)K_;
        const double mean = s / n;
        const double var  = q / n - mean * mean;      // biased, matches ref
        const double sc   = fabs((double)gamma[tid]) / sqrt(var + BN_EPS);
        sc_s[tid] = (float)sc;
        sh_s[tid] = (float)((double)beta[tid] - mean * sc);
    }
    __syncthreads();

    const int idx = blockIdx.x * 256 + tid;           // over B*C, c fastest
    const int c = idx & (C_ - 1);
    const float sc = sc_s[c];
    const float sh = sh_s[c];
    if (sc == 0.0f) {                                 // gamma==0 degenerate
        out[idx] = 0.0f;
        out[(size_t)BC_ + idx] = sh;
    } else {
        out[(size_t)BC_ + idx] = fmaf(out[(size_t)BC_ + idx], sc, sh);
    }

    // centroid passthrough: 1M floats = 256K float4, first 256K threads
    if (idx < (C_ * K_ * D_) / 4) {
        ((float4*)(out + 2 * (size_t)BC_))[idx] = ((const float4*)cent)[idx];
    }
}

// ---------------------------------------------------------------------------
extern "C" void kernel_launch(void* const* d_in, const int* in_sizes, int n_in,
                              void* d_out, int out_size, void* d_ws, size_t ws_size,
                              hipStream_t stream)
{
    const float* x     = (const float*)d_in[0];
    const float* cent  = (const float*)d_in[1];
    const float* gamma = (const float*)d_in[2];
    const float* beta  = (const float*)d_in[3];
    float* out = (float*)d_out;
    float* ws  = (float*)d_ws;

    // ws layout (4B units): [0,4096) csum | [4096,5120) part_sum
    // [5120,6144) part_sq | [6144,6208) wcount[64] | [6208, +64*WCAP_C) worklist
    float* csum     = ws;
    float* part_sum = ws + 4096;
    float* part_sq  = ws + 5120;
    int*   wcount   = (int*)(ws + 6144);
    int*   worklist = (int*)(ws + 6208);

    hipLaunchKernelGGL(dpq_prep, dim3(C_), dim3(256), 0, stream,
                       cent, csum, wcount);
    dim3 g1(GX, C_);   // (16, 64)
    hipLaunchKernelGGL(dpq_mfma, g1, dim3(512), 0, stream,
                       x, cent, gamma, csum, out, part_sum, part_sq,
                       wcount, worklist);
    hipLaunchKernelGGL(dpq_referee, dim3(C_, 4), dim3(256), 0, stream,
                       x, cent, gamma, wcount, worklist, out);
    hipLaunchKernelGGL(dpq_apply, dim3(BC_ / 256), dim3(256), 0, stream,
                       out, part_sum, part_sq, gamma, beta, cent);
}

// Round 11
// 101.243 us; speedup vs baseline: 1.0801x; 1.0801x over previous
//
#include <hip/hip_runtime.h>

// Problem constants
#define B_  8192
#define C_  64
#define K_  256
#define D_  64
#define WROWS 64               // b-rows per wave (4 MFMA sub-tiles)
#define GX  (B_ / (8 * WROWS)) // 16 blocks along b (8 waves/block)
#define BC_ (B_ * C_)
#define BN_EPS 1e-5

#define WCAP_C 1024            // per-channel referee list capacity
#define DELTA  2.5e-3f         // top-2 gap flag band (validated r4/r9)

typedef _Float16 f16x8 __attribute__((ext_vector_type(8)));
typedef float    f32x4 __attribute__((ext_vector_type(4)));

// XOR swizzle for [row][128B] f16 plane: kills 32-way bank conflict on b128.
__device__ __forceinline__ int swz(int row, int dbyte) {
    return (row * 128 + dbyte) ^ ((row & 7) << 4);
}

// plain-cast f32x8 -> f16x8 (known-good RTNE conversion)
__device__ __forceinline__ f16x8 cvt8(const float* p) {
    float4 u0 = *(const float4*)p;
    float4 u1 = *(const float4*)(p + 4);
    return (f16x8){(_Float16)u0.x, (_Float16)u0.y, (_Float16)u0.z, (_Float16)u0.w,
                   (_Float16)u1.x, (_Float16)u1.y, (_Float16)u1.z, (_Float16)u1.w};
}

// merge two packed (best, second) pairs over disjoint k-sets
#define MERGE2(B1, S1, B2, S2)                                              \
    {                                                                       \
        const float lo_ = fminf(B1, B2);                                    \
        B1 = fmaxf(B1, B2);                                                 \
        S1 = fmaxf(lo_, fmaxf(S1, S2));                                     \
    }

// ---------------------------------------------------------------------------
// Prep: per-channel centroid column sums + zero referee counters.
// ---------------------------------------------------------------------------
__global__ __launch_bounds__(256) void dpq_prep(
    const float* __restrict__ cent, float* __restrict__ csum,
    int* __restrict__ wcount)
{
    __shared__ float pacc[4][D_];
    const int c = blockIdx.x, t = threadIdx.x;
    const int d = t & 63, seg = t >> 6;
    const float* g = cent + (size_t)c * K_ * D_ + (size_t)seg * 64 * D_ + d;
    float s = 0.f;
#pragma unroll 8
    for (int k = 0; k < 64; ++k) s += g[(size_t)k * D_];
    pacc[seg][d] = s;
    __syncthreads();
    if (t < D_)
        csum[c * D_ + t] = (pacc[0][t] + pacc[1][t]) + (pacc[2][t] + pacc[3][t]);
    if (t == 0) wcount[c] = 0;
}

// ---------------------------------------------------------------------------
// Pass 1: single-pass f16 MFMA scoring. 512 thr, 32 KiB plane + 2 KiB cs-tile.
// XCD channel-affinity swizzle: channel c's 16 blocks land on ONE XCD ->
// centroids + x-slice become L2-local. setprio(1) around the MFMA cluster.
// ---------------------------------------------------------------------------
__global__ __launch_bounds__(512, 6) void dpq_mfma(
    const float* __restrict__ x,        // (B, C, D)
    const float* __restrict__ cent,     // (C, K, D)
    const float* __restrict__ gamma,    // (C)
    const float* __restrict__ csum,     // (C, D) centroid column sums
    float* __restrict__ out,            // [codes BC][raw mse BC][centroids]
    float* __restrict__ part_sum,       // (C, GX)
    float* __restrict__ part_sq,        // (C, GX)
    int* __restrict__ wcount,           // (C)
    int* __restrict__ worklist)         // (C, WCAP_C) stores b
{
    __shared__ char lds[34816];         // [0,32K) k-plane | [32K,34K) cs-tile
    // XCD swizzle: lid consecutive -> consecutive c; same-c blocks differ by
    // 64 in lid -> same (lid % 8) -> same XCD. Bijective (1024 blocks).
    const int lid = blockIdx.x + GX * blockIdx.y;
    const int c   = lid & 63;
    const int bxv = lid >> 6;
    const int tid = threadIdx.x;
    const float sgn = (gamma[c] < 0.0f) ? -1.0f : 1.0f;   // fold BN sign

    // ---- stage centroids: 512 threads, each converts half a k-row ----
    {
        const int row = tid >> 1, half = tid & 1;
        const float* g = cent + ((size_t)c * K_ + row) * D_ + half * 32;
#pragma unroll
        for (int q = 0; q < 4; ++q) {
            float v[8];
#pragma unroll
            for (int j = 0; j < 8; ++j) v[j] = g[q * 8 + j] * sgn;
            f16x8 h = {(_Float16)v[0], (_Float16)v[1], (_Float16)v[2], (_Float16)v[3],
                       (_Float16)v[4], (_Float16)v[5], (_Float16)v[6], (_Float16)v[7]};
            *(f16x8*)(lds + swz(row, half * 64 + q * 16)) = h;
        }
    }
    // ---- stage cs-tile: row 0 = sign-folded centroid sum, rows 1-15 = 0 ----
    if (tid < 128) {
        const int row = tid >> 3, q = tid & 7;
        f16x8 h = {0, 0, 0, 0, 0, 0, 0, 0};
        if (row == 0) {
            const float* cs = csum + c * D_ + q * 8;
#pragma unroll
            for (int j = 0; j < 8; ++j) h[j] = (_Float16)(cs[j] * sgn);
        }
        *(f16x8*)(lds + 32768 + swz(row, q * 16)) = h;
    }
    __syncthreads();

    const int wid = tid >> 6, lane = tid & 63;
    const int col = lane & 15, grp = lane >> 4;
    const unsigned g4 = (unsigned)(grp * 4);
    const int b0 = bxv * (8 * WROWS) + wid * WROWS;

    // x fragments: 4 b-subtiles (T) x 2 d-halves
    f16x8 xfa[4], xfb[4];
    {
        const float* xb = x + ((size_t)(b0 + col) * C_ + c) * D_ + grp * 8;
        const size_t st16 = (size_t)16 * C_ * D_;
#pragma unroll
        for (int T = 0; T < 4; ++T) {
            xfa[T] = cvt8(xb + T * st16);
            xfb[T] = cvt8(xb + T * st16 + 32);
        }
    }

    float taccs[4] = {0.f, 0.f, 0.f, 0.f};   // fed by virtual sum-step only
    float taccq[4] = {0.f, 0.f, 0.f, 0.f};
    float bestv[4], secv[4];
#pragma unroll
    for (int T = 0; T < 4; ++T) { bestv[T] = -3.4e38f; secv[T] = -3.4e38f; }

#pragma unroll 4
    for (int t = 0; t < 16; ++t) {
        const f16x8 a0 = *(const f16x8*)(lds + swz(t * 16 + col,      grp * 16));
        const f16x8 a1 = *(const f16x8*)(lds + swz(t * 16 + col, 64 + grp * 16));
        const unsigned kt = ((unsigned)t << 4) | g4;   // t*16 + grp*4

        // clustered MFMAs under raised priority (T5: non-lockstep waves)
        f32x4 p[4];
        __builtin_amdgcn_s_setprio(1);
#pragma unroll
        for (int T = 0; T < 4; ++T) {
            f32x4 acc = {0.f, 0.f, 0.f, 0.f};
            acc = __builtin_amdgcn_mfma_f32_16x16x32_f16(a0, xfa[T], acc, 0, 0, 0);
            acc = __builtin_amdgcn_mfma_f32_16x16x32_f16(a1, xfb[T], acc, 0, 0, 0);
            p[T] = acc;
        }
        __builtin_amdgcn_s_setprio(0);

#pragma unroll
        for (int j = 0; j < 4; ++j) {
            const unsigned kj = kt + j;
#pragma unroll
            for (int T = 0; T < 4; ++T) {
                const float r = p[T][j];
                taccq[T] = fmaf(r, r, taccq[T]);
                const float pk = __uint_as_float(
                    (__float_as_uint(r) & 0xFFFFFF00u) | kj);
                secv[T]  = __builtin_amdgcn_fmed3f(pk, bestv[T], secv[T]);
                bestv[T] = fmaxf(bestv[T], pk);
            }
        }
    }

    // ---- virtual sum-step: row 0 of cs-tile = sum over all k ----
    {
        const f16x8 a0v = *(const f16x8*)(lds + 32768 + swz(col,      grp * 16));
        const f16x8 a1v = *(const f16x8*)(lds + 32768 + swz(col, 64 + grp * 16));
#pragma unroll
        for (int T = 0; T < 4; ++T) {
            f32x4 pv = {0.f, 0.f, 0.f, 0.f};
            pv = __builtin_amdgcn_mfma_f32_16x16x32_f16(a0v, xfa[T], pv, 0, 0, 0);
            pv = __builtin_amdgcn_mfma_f32_16x16x32_f16(a1v, xfb[T], pv, 0, 0, 0);
            taccs[T] += pv[0];   // nonzero only on k-row-0 lanes
        }
    }

    // ---- cross-lane top-2 merge (same-col lanes differ in bits 4,5) ----
#pragma unroll
    for (int T = 0; T < 4; ++T) {
        float bv = bestv[T], sv = secv[T];
#pragma unroll
        for (int m = 16; m <= 32; m <<= 1) {
            const float ob = __shfl_xor(bv, m);
            const float os = __shfl_xor(sv, m);
            MERGE2(bv, sv, ob, os);
        }
        if (grp == 0) {
            const int b = b0 + T * 16 + col;
            const size_t idx = (size_t)b * C_ + c;
            const unsigned bits = __float_as_uint(bv);
            out[idx] = (float)(bits & 255u);                       // code
            out[(size_t)BC_ + idx] = __uint_as_float(bits & 0xFFFFFF00u);
            if (bv - sv < DELTA) {
                const int slot = atomicAdd(&wcount[c], 1);
                if (slot < WCAP_C) worklist[c * WCAP_C + slot] = b;
            }
        }
    }

    // ---- channel sum / sumsq block reduction ----
    float accs = (taccs[0] + taccs[1]) + (taccs[2] + taccs[3]);
    float accq = (taccq[0] + taccq[1]) + (taccq[2] + taccq[3]);
#pragma unroll
    for (int m = 1; m <= 32; m <<= 1) {
        accs += __shfl_xor(accs, m);
        accq += __shfl_xor(accq, m);
    }
    __syncthreads();                    // plane dead; reuse LDS
    float* red = (float*)lds;
    if (lane == 0) { red[wid] = accs; red[8 + wid] = accq; }
    __syncthreads();
    if (tid == 0) {
        float s = 0.f, q = 0.f;
#pragma unroll
        for (int w = 0; w < 8; ++w) { s += red[w]; q += red[8 + w]; }
        part_sum[c * GX + bxv] = s;
        part_sq [c * GX + bxv] = q;
    }
}

// ---------------------------------------------------------------------------
// Referee: exact fp64 re-score of flagged pairs, channel-bucketed.
// ---------------------------------------------------------------------------
__global__ __launch_bounds__(256) void dpq_referee(
    const float* __restrict__ x,
    const float* __restrict__ cent,
    const float* __restrict__ gamma,
    const int* __restrict__ wcount,
    const int* __restrict__ worklist,
    float* __restrict__ out)
{
    __shared__ float cl[K_ * D_];       // 64 KiB exact centroids
    const int c = blockIdx.x;
    int n = wcount[c];
    if (n > WCAP_C) n = WCAP_C;
    if (n <= 0) return;
    const int t = threadIdx.x;          // 0..255 = k row to stage
    const float sgnf = (gamma[c] < 0.0f) ? -1.0f : 1.0f;

    // stage row t with d-swizzle (d ^ (k&31)) -> conflict-free lane reads
    {
        const float* g = cent + ((size_t)c * K_ + t) * D_;
#pragma unroll 8
        for (int d = 0; d < D_; ++d)
            cl[t * D_ + (d ^ (t & 31))] = g[d];
    }
    __syncthreads();

    const int wid = t >> 6, lane = t & 63;
    for (int i = blockIdx.y * 4 + wid; i < n; i += gridDim.y * 4) {
        const int b = worklist[c * WCAP_C + i];
        const float* xr = x + ((size_t)b * C_ + c) * D_;
        double bv = -1.0e300;
        int bk = 0;
#pragma unroll
        for (int q = 0; q < 4; ++q) {
            const int k = q * 64 + lane;            // ascending per lane
            const int sw = k & 31;
            double s = 0.0;
#pragma unroll 8
            for (int d = 0; d < D_; ++d)
                s += (double)xr[d] * (double)cl[k * D_ + (d ^ sw)];
            s *= (double)sgnf;
            if (s > bv) { bv = s; bk = k; }
        }
#pragma unroll
        for (int m = 1; m <= 32; m <<= 1) {
            const double ov = __shfl_xor(bv, m);
            const int   ok = __shfl_xor(bk, m);
            if (ov > bv || (ov == bv && ok < bk)) { bv = ov; bk = ok; }
        }
        if (lane == 0) {
            const size_t idx = (size_t)b * C_ + c;
            out[idx] = (float)bk;
            out[(size_t)BC_ + idx] = (float)bv;
        }
    }
}

// ---------------------------------------------------------------------------
// Apply (fused stats + affine + centroid passthrough).
// ---------------------------------------------------------------------------
__global__ __launch_bounds__(256) void dpq_apply(
    float* __restrict__ out,
    const float* __restrict__ part_sum,
    const float* __restrict__ part_sq,
    const float* __restrict__ gamma,
    const float* __restrict__ beta,
    const float* __restrict__ cent)
{
    __shared__ float sc_s[C_], sh_s[C_];
    const int tid = threadIdx.x;
    if (tid < C_) {
        double s = 0.0, q = 0.0;
#pragma unroll
        for (int i = 0; i < GX; ++i) {
            s += (double)part_sum[tid * GX + i];
            q += (double)part_sq [tid * GX + i];
        }
        const double n    = (double)B_ * (double)K_;
        const double mean = s / n;
        const double var  = q / n - mean * mean;      // biased, matches ref
        const double sc   = fabs((double)gamma[tid]) / sqrt(var + BN_EPS);
        sc_s[tid] = (float)sc;
        sh_s[tid] = (float)((double)beta[tid] - mean * sc);
    }
    __syncthreads();

    const int idx = blockIdx.x * 256 + tid;           // over B*C, c fastest
    const int c = idx & (C_ - 1);
    const float sc = sc_s[c];
    const float sh = sh_s[c];
    if (sc == 0.0f) {                                 // gamma==0 degenerate
        out[idx] = 0.0f;
        out[(size_t)BC_ + idx] = sh;
    } else {
        out[(size_t)BC_ + idx] = fmaf(out[(size_t)BC_ + idx], sc, sh);
    }

    // centroid passthrough: 1M floats = 256K float4, first 256K threads
    if (idx < (C_ * K_ * D_) / 4) {
        ((float4*)(out + 2 * (size_t)BC_))[idx] = ((const float4*)cent)[idx];
    }
}

// ---------------------------------------------------------------------------
extern "C" void kernel_launch(void* const* d_in, const int* in_sizes, int n_in,
                              void* d_out, int out_size, void* d_ws, size_t ws_size,
                              hipStream_t stream)
{
    const float* x     = (const float*)d_in[0];
    const float* cent  = (const float*)d_in[1];
    const float* gamma = (const float*)d_in[2];
    const float* beta  = (const float*)d_in[3];
    float* out = (float*)d_out;
    float* ws  = (float*)d_ws;

    // ws layout (4B units): [0,4096) csum | [4096,5120) part_sum
    // [5120,6144) part_sq | [6144,6208) wcount[64] | [6208, +64*WCAP_C) worklist
    float* csum     = ws;
    float* part_sum = ws + 4096;
    float* part_sq  = ws + 5120;
    int*   wcount   = (int*)(ws + 6144);
    int*   worklist = (int*)(ws + 6208);

    hipLaunchKernelGGL(dpq_prep, dim3(C_), dim3(256), 0, stream,
                       cent, csum, wcount);
    dim3 g1(GX, C_);   // (16, 64) -> swizzled inside kernel
    hipLaunchKernelGGL(dpq_mfma, g1, dim3(512), 0, stream,
                       x, cent, gamma, csum, out, part_sum, part_sq,
                       wcount, worklist);
    hipLaunchKernelGGL(dpq_referee, dim3(C_, 4), dim3(256), 0, stream,
                       x, cent, gamma, wcount, worklist, out);
    hipLaunchKernelGGL(dpq_apply, dim3(BC_ / 256), dim3(256), 0, stream,
                       out, part_sum, part_sq, gamma, beta, cent);
}

// Round 12
// 100.156 us; speedup vs baseline: 1.0918x; 1.0109x over previous
//
#include <hip/hip_runtime.h>

// Problem constants
#define B_  8192
#define C_  64
#define K_  256
#define D_  64
#define WROWS 64               // b-rows per wave (4 MFMA sub-tiles)
#define GX  (B_ / (8 * WROWS)) // 16 blocks along b (8 waves/block)
#define BC_ (B_ * C_)
#define BN_EPS 1e-5

#define WCAP_C 1024            // per-channel referee list capacity
#define DELTA  2.5e-3f         // top-2 gap flag band (validated r4/r9)

typedef _Float16 f16x8 __attribute__((ext_vector_type(8)));
typedef float    f32x4 __attribute__((ext_vector_type(4)));

// XOR swizzle for [row][128B] f16 plane: kills 32-way bank conflict on b128.
__device__ __forceinline__ int swz(int row, int dbyte) {
    return (row * 128 + dbyte) ^ ((row & 7) << 4);
}

// plain-cast f32x8 -> f16x8 (known-good RTNE conversion)
__device__ __forceinline__ f16x8 cvt8(const float* p) {
    float4 u0 = *(const float4*)p;
    float4 u1 = *(const float4*)(p + 4);
    return (f16x8){(_Float16)u0.x, (_Float16)u0.y, (_Float16)u0.z, (_Float16)u0.w,
                   (_Float16)u1.x, (_Float16)u1.y, (_Float16)u1.z, (_Float16)u1.w};
}

// merge two packed (best, second) pairs over disjoint k-sets
#define MERGE2(B1, S1, B2, S2)                                              \
    {                                                                       \
        const float lo_ = fminf(B1, B2);                                    \
        B1 = fmaxf(B1, B2);                                                 \
        S1 = fmaxf(lo_, fmaxf(S1, S2));                                     \
    }

// ---------------------------------------------------------------------------
// Prep: per-channel centroid column sums + zero referee counters.
// ---------------------------------------------------------------------------
__global__ __launch_bounds__(256) void dpq_prep(
    const float* __restrict__ cent, float* __restrict__ csum,
    int* __restrict__ wcount)
{
    __shared__ float pacc[4][D_];
    const int c = blockIdx.x, t = threadIdx.x;
    const int d = t & 63, seg = t >> 6;
    const float* g = cent + (size_t)c * K_ * D_ + (size_t)seg * 64 * D_ + d;
    float s = 0.f;
#pragma unroll 8
    for (int k = 0; k < 64; ++k) s += g[(size_t)k * D_];
    pacc[seg][d] = s;
    __syncthreads();
    if (t < D_)
        csum[c * D_ + t] = (pacc[0][t] + pacc[1][t]) + (pacc[2][t] + pacc[3][t]);
    if (t == 0) wcount[c] = 0;
}

// ---------------------------------------------------------------------------
// Pass 1: single-pass f16 MFMA scoring. 512 thr, 32 KiB plane + 2 KiB cs-tile.
// Output: ONE packed (value|k) float per (b,c) into ws_pk[c*B + b] ->
// 16-lane clusters write exactly one 64-B line (no 4B-scatter write-allocate).
// ---------------------------------------------------------------------------
__global__ __launch_bounds__(512, 6) void dpq_mfma(
    const float* __restrict__ x,        // (B, C, D)
    const float* __restrict__ cent,     // (C, K, D)
    const float* __restrict__ gamma,    // (C)
    const float* __restrict__ csum,     // (C, D) centroid column sums
    float* __restrict__ ws_pk,          // (C, B) packed value|k
    float* __restrict__ part_sum,       // (C, GX)
    float* __restrict__ part_sq,        // (C, GX)
    int* __restrict__ wcount,           // (C)
    int* __restrict__ worklist)         // (C, WCAP_C) stores b
{
    __shared__ char lds[34816];         // [0,32K) k-plane | [32K,34K) cs-tile
    // XCD swizzle: same-c blocks -> same XCD (bijective, 1024 blocks).
    const int lid = blockIdx.x + GX * blockIdx.y;
    const int c   = lid & 63;
    const int bxv = lid >> 6;
    const int tid = threadIdx.x;
    const float sgn = (gamma[c] < 0.0f) ? -1.0f : 1.0f;   // fold BN sign

    // ---- stage centroids: 512 threads, each converts half a k-row ----
    {
        const int row = tid >> 1, half = tid & 1;
        const float* g = cent + ((size_t)c * K_ + row) * D_ + half * 32;
#pragma unroll
        for (int q = 0; q < 4; ++q) {
            float v[8];
#pragma unroll
            for (int j = 0; j < 8; ++j) v[j] = g[q * 8 + j] * sgn;
            f16x8 h = {(_Float16)v[0], (_Float16)v[1], (_Float16)v[2], (_Float16)v[3],
                       (_Float16)v[4], (_Float16)v[5], (_Float16)v[6], (_Float16)v[7]};
            *(f16x8*)(lds + swz(row, half * 64 + q * 16)) = h;
        }
    }
    // ---- stage cs-tile: row 0 = sign-folded centroid sum, rows 1-15 = 0 ----
    if (tid < 128) {
        const int row = tid >> 3, q = tid & 7;
        f16x8 h = {0, 0, 0, 0, 0, 0, 0, 0};
        if (row == 0) {
            const float* cs = csum + c * D_ + q * 8;
#pragma unroll
            for (int j = 0; j < 8; ++j) h[j] = (_Float16)(cs[j] * sgn);
        }
        *(f16x8*)(lds + 32768 + swz(row, q * 16)) = h;
    }
    __syncthreads();

    const int wid = tid >> 6, lane = tid & 63;
    const int col = lane & 15, grp = lane >> 4;
    const unsigned g4 = (unsigned)(grp * 4);
    const int b0 = bxv * (8 * WROWS) + wid * WROWS;

    // x fragments: 4 b-subtiles (T) x 2 d-halves
    f16x8 xfa[4], xfb[4];
    {
        const float* xb = x + ((size_t)(b0 + col) * C_ + c) * D_ + grp * 8;
        const size_t st16 = (size_t)16 * C_ * D_;
#pragma unroll
        for (int T = 0; T < 4; ++T) {
            xfa[T] = cvt8(xb + T * st16);
            xfb[T] = cvt8(xb + T * st16 + 32);
        }
    }

    float taccs[4] = {0.f, 0.f, 0.f, 0.f};   // fed by virtual sum-step only
    float taccq[4] = {0.f, 0.f, 0.f, 0.f};
    float bestv[4], secv[4];
#pragma unroll
    for (int T = 0; T < 4; ++T) { bestv[T] = -3.4e38f; secv[T] = -3.4e38f; }

#pragma unroll 4
    for (int t = 0; t < 16; ++t) {
        const f16x8 a0 = *(const f16x8*)(lds + swz(t * 16 + col,      grp * 16));
        const f16x8 a1 = *(const f16x8*)(lds + swz(t * 16 + col, 64 + grp * 16));
        const unsigned kt = ((unsigned)t << 4) | g4;   // t*16 + grp*4

        f32x4 p[4];
        __builtin_amdgcn_s_setprio(1);
#pragma unroll
        for (int T = 0; T < 4; ++T) {
            f32x4 acc = {0.f, 0.f, 0.f, 0.f};
            acc = __builtin_amdgcn_mfma_f32_16x16x32_f16(a0, xfa[T], acc, 0, 0, 0);
            acc = __builtin_amdgcn_mfma_f32_16x16x32_f16(a1, xfb[T], acc, 0, 0, 0);
            p[T] = acc;
        }
        __builtin_amdgcn_s_setprio(0);

#pragma unroll
        for (int j = 0; j < 4; ++j) {
            const unsigned kj = kt + j;
#pragma unroll
            for (int T = 0; T < 4; ++T) {
                const float r = p[T][j];
                taccq[T] = fmaf(r, r, taccq[T]);
                const float pk = __uint_as_float(
                    (__float_as_uint(r) & 0xFFFFFF00u) | kj);
                secv[T]  = __builtin_amdgcn_fmed3f(pk, bestv[T], secv[T]);
                bestv[T] = fmaxf(bestv[T], pk);
            }
        }
    }

    // ---- virtual sum-step: row 0 of cs-tile = sum over all k ----
    {
        const f16x8 a0v = *(const f16x8*)(lds + 32768 + swz(col,      grp * 16));
        const f16x8 a1v = *(const f16x8*)(lds + 32768 + swz(col, 64 + grp * 16));
#pragma unroll
        for (int T = 0; T < 4; ++T) {
            f32x4 pv = {0.f, 0.f, 0.f, 0.f};
            pv = __builtin_amdgcn_mfma_f32_16x16x32_f16(a0v, xfa[T], pv, 0, 0, 0);
            pv = __builtin_amdgcn_mfma_f32_16x16x32_f16(a1v, xfb[T], pv, 0, 0, 0);
            taccs[T] += pv[0];   // nonzero only on k-row-0 lanes
        }
    }

    // ---- cross-lane top-2 merge (same-col lanes differ in bits 4,5) ----
#pragma unroll
    for (int T = 0; T < 4; ++T) {
        float bv = bestv[T], sv = secv[T];
#pragma unroll
        for (int m = 16; m <= 32; m <<= 1) {
            const float ob = __shfl_xor(bv, m);
            const float os = __shfl_xor(sv, m);
            MERGE2(bv, sv, ob, os);
        }
        if (grp == 0) {
            const int b = b0 + T * 16 + col;
            ws_pk[(size_t)c * B_ + b] = bv;     // coalesced: one line/16 lanes
            if (bv - sv < DELTA) {
                const int slot = atomicAdd(&wcount[c], 1);
                if (slot < WCAP_C) worklist[c * WCAP_C + slot] = b;
            }
        }
    }

    // ---- channel sum / sumsq block reduction ----
    float accs = (taccs[0] + taccs[1]) + (taccs[2] + taccs[3]);
    float accq = (taccq[0] + taccq[1]) + (taccq[2] + taccq[3]);
#pragma unroll
    for (int m = 1; m <= 32; m <<= 1) {
        accs += __shfl_xor(accs, m);
        accq += __shfl_xor(accq, m);
    }
    __syncthreads();                    // plane dead; reuse LDS
    float* red = (float*)lds;
    if (lane == 0) { red[wid] = accs; red[8 + wid] = accq; }
    __syncthreads();
    if (tid == 0) {
        float s = 0.f, q = 0.f;
#pragma unroll
        for (int w = 0; w < 8; ++w) { s += red[w]; q += red[8 + w]; }
        part_sum[c * GX + bxv] = s;
        part_sq [c * GX + bxv] = q;
    }
}

// ---------------------------------------------------------------------------
// Referee: exact fp64 re-score of flagged pairs, channel-bucketed.
// Writes the exact result as a packed (value|k) float into ws_pk.
// ---------------------------------------------------------------------------
__global__ __launch_bounds__(256) void dpq_referee(
    const float* __restrict__ x,
    const float* __restrict__ cent,
    const float* __restrict__ gamma,
    const int* __restrict__ wcount,
    const int* __restrict__ worklist,
    float* __restrict__ ws_pk)
{
    __shared__ float cl[K_ * D_];       // 64 KiB exact centroids
    const int c = blockIdx.x;
    int n = wcount[c];
    if (n > WCAP_C) n = WCAP_C;
    if (n <= 0) return;
    const int t = threadIdx.x;          // 0..255 = k row to stage
    const float sgnf = (gamma[c] < 0.0f) ? -1.0f : 1.0f;

    // stage row t with d-swizzle (d ^ (k&31)) -> conflict-free lane reads
    {
        const float* g = cent + ((size_t)c * K_ + t) * D_;
#pragma unroll 8
        for (int d = 0; d < D_; ++d)
            cl[t * D_ + (d ^ (t & 31))] = g[d];
    }
    __syncthreads();

    const int wid = t >> 6, lane = t & 63;
    for (int i = blockIdx.y * 4 + wid; i < n; i += gridDim.y * 4) {
        const int b = worklist[c * WCAP_C + i];
        const float* xr = x + ((size_t)b * C_ + c) * D_;
        double bv = -1.0e300;
        int bk = 0;
#pragma unroll
        for (int q = 0; q < 4; ++q) {
            const int k = q * 64 + lane;            // ascending per lane
            const int sw = k & 31;
            double s = 0.0;
#pragma unroll 8
            for (int d = 0; d < D_; ++d)
                s += (double)xr[d] * (double)cl[k * D_ + (d ^ sw)];
            s *= (double)sgnf;
            if (s > bv) { bv = s; bk = k; }
        }
#pragma unroll
        for (int m = 1; m <= 32; m <<= 1) {
            const double ov = __shfl_xor(bv, m);
            const int   ok = __shfl_xor(bk, m);
            if (ov > bv || (ov == bv && ok < bk)) { bv = ov; bk = ok; }
        }
        if (lane == 0) {
            const unsigned bits =
                (__float_as_uint((float)bv) & 0xFFFFFF00u) | (unsigned)bk;
            ws_pk[(size_t)c * B_ + b] = __uint_as_float(bits);
        }
    }
}

// ---------------------------------------------------------------------------
// Apply (fused stats + unpack + affine + centroid passthrough).
// Reads ws_pk transposed (4x-amplified but tiny & cached); writes out
// fully coalesced (wave = 256 B contiguous -> full-line, no RFO).
// ---------------------------------------------------------------------------
__global__ __launch_bounds__(256) void dpq_apply(
    float* __restrict__ out,
    const float* __restrict__ ws_pk,
    const float* __restrict__ part_sum,
    const float* __restrict__ part_sq,
    const float* __restrict__ gamma,
    const float* __restrict__ beta,
    const float* __restrict__ cent)
{
    __shared__ float sc_s[C_], sh_s[C_];
    const int tid = threadIdx.x;
    if (tid < C_) {
        double s = 0.0, q = 0.0;
#pragma unroll
        for (int i = 0; i < GX; ++i) {
            s += (double)part_sum[tid * GX + i];
            q += (double)part_sq [tid * GX + i];
        }
        const double n    = (double)B_ * (double)K_;
        const double mean = s / n;
        const double var  = q / n - mean * mean;      // biased, matches ref
        const double sc   = fabs((double)gamma[tid]) / sqrt(var + BN_EPS);
        sc_s[tid] = (float)sc;
        sh_s[tid] = (float)((double)beta[tid] - mean * sc);
    }
    __syncthreads();

    const int g = blockIdx.x * 256 + tid;             // g = b*64 + c
    const int c = g & (C_ - 1);
    const int b = g >> 6;
    const unsigned bits = __float_as_uint(ws_pk[(size_t)c * B_ + b]);
    const float raw = __uint_as_float(bits & 0xFFFFFF00u);
    const float sc = sc_s[c];
    const float sh = sh_s[c];
    if (sc == 0.0f) {                                 // gamma==0 degenerate
        out[g] = 0.0f;
        out[(size_t)BC_ + g] = sh;
    } else {
        out[g] = (float)(bits & 255u);                // code
        out[(size_t)BC_ + g] = fmaf(raw, sc, sh);     // mse
    }

    // centroid passthrough: 1M floats = 256K float4, first 256K threads
    if (g < (C_ * K_ * D_) / 4) {
        ((float4*)(out + 2 * (size_t)BC_))[g] = ((const float4*)cent)[g];
    }
}

// ---------------------------------------------------------------------------
extern "C" void kernel_launch(void* const* d_in, const int* in_sizes, int n_in,
                              void* d_out, int out_size, void* d_ws, size_t ws_size,
                              hipStream_t stream)
{
    const float* x     = (const float*)d_in[0];
    const float* cent  = (const float*)d_in[1];
    const float* gamma = (const float*)d_in[2];
    const float* beta  = (const float*)d_in[3];
    float* out = (float*)d_out;
    float* ws  = (float*)d_ws;

    // ws layout (4B units): [0,4096) csum | [4096,5120) part_sum
    // [5120,6144) part_sq | [6144,6208) wcount[64]
    // [6208,71744) worklist | [71744, 71744+BC_) ws_pk
    float* csum     = ws;
    float* part_sum = ws + 4096;
    float* part_sq  = ws + 5120;
    int*   wcount   = (int*)(ws + 6144);
    int*   worklist = (int*)(ws + 6208);
    float* ws_pk    = ws + 71744;

    hipLaunchKernelGGL(dpq_prep, dim3(C_), dim3(256), 0, stream,
                       cent, csum, wcount);
    dim3 g1(GX, C_);   // (16, 64) -> swizzled inside kernel
    hipLaunchKernelGGL(dpq_mfma, g1, dim3(512), 0, stream,
                       x, cent, gamma, csum, ws_pk, part_sum, part_sq,
                       wcount, worklist);
    hipLaunchKernelGGL(dpq_referee, dim3(C_, 4), dim3(256), 0, stream,
                       x, cent, gamma, wcount, worklist, ws_pk);
    hipLaunchKernelGGL(dpq_apply, dim3(BC_ / 256), dim3(256), 0, stream,
                       out, ws_pk, part_sum, part_sq, gamma, beta, cent);
}